// Round 13
// baseline (2470.317 us; speedup 1.0000x reference)
//
#include <hip/hip_runtime.h>

// Model: B=32, L1=512, L2=16, D=300, H=300, V=50000, C=3
#define B_  32
#define L1_ 512
#define L2_ 16
#define D_  300
#define H_  300

__device__ __forceinline__ float sigmoid_fast(float x) {
    return 1.0f / (1.0f + __expf(-x));
}
__device__ __forceinline__ float tanh_fast(float x) {
    x = fminf(fmaxf(x, -15.0f), 15.0f);
    float e = __expf(2.0f * x);
    return (e - 1.0f) / (e + 1.0f);
}
// accurate versions for the GRU recurrence (R4/R5/R7 evidence: large margin)
__device__ __forceinline__ float sigmoid_acc(float x) {
    return 1.0f / (1.0f + expf(-x));
}
__device__ __forceinline__ float wred_sum(float v) {
    #pragma unroll
    for (int off = 32; off > 0; off >>= 1) v += __shfl_xor(v, off);
    return v;
}
__device__ __forceinline__ float wred_max(float v) {
    #pragma unroll
    for (int off = 32; off > 0; off >>= 1) v = fmaxf(v, __shfl_xor(v, off));
    return v;
}

// device-coherent (LLC) 8-byte packet ops: sc0 sc1 = bypass L1+L2, no invalidates
__device__ __forceinline__ void store_pkt(long long* p, long long v) {
    asm volatile("global_store_dwordx2 %0, %1, off sc0 sc1" :: "v"(p), "v"(v) : "memory");
}
// two tagged loads in flight, one wait
__device__ __forceinline__ void load_pkt2(const long long* p1, const long long* p2,
                                          long long& v1, long long& v2) {
    asm volatile("global_load_dwordx2 %0, %2, off sc0 sc1\n\t"
                 "global_load_dwordx2 %1, %3, off sc0 sc1\n\t"
                 "s_waitcnt vmcnt(0)"
                 : "=&v"(v1), "=&v"(v2) : "v"(p1), "v"(p2) : "memory");
}

// Workgroup barrier that drains ONLY lgkmcnt (LDS), not vmcnt: keeps publish
// store ACKs off the barrier critical path (tag protocol owns global
// visibility). sched_barrier + memory clobber fence compiler motion (rule #18).
__device__ __forceinline__ void wg_barrier() {
    __builtin_amdgcn_sched_barrier(0);
    asm volatile("s_waitcnt lgkmcnt(0)" ::: "memory");
    __builtin_amdgcn_s_barrier();
    __builtin_amdgcn_sched_barrier(0);
}

// ---------------- gather rows of emb (row length 300 = 75 float4) ----------------
__global__ __launch_bounds__(256) void gather_kernel(const float* __restrict__ emb,
                                                     const int* __restrict__ ids,
                                                     float* __restrict__ out, int total) {
    for (int i = blockIdx.x * 256 + threadIdx.x; i < total; i += gridDim.x * 256) {
        int row = i / 75, c = i % 75;
        int id = ids[row];
        reinterpret_cast<float4*>(out)[i] =
            reinterpret_cast<const float4*>(emb + (size_t)id * 300)[c];
    }
}

// ---------------- fp32 GEMM (R7-proven): C[M,N] = A[M,K] @ W[N,K]^T (+ bias) ----------------
// Reverted to the measured-best config: 128x64 tile, 8x4 microtile, VGPR=40,
// 8 waves/SIMD occupancy (R11/R12 evidence: 8x8-microtile variants at ~3
// waves/SIMD are net slower on these K=300 shapes despite better FMA density).
#define TM 128
#define TN 64
#define TK 16
__global__ __launch_bounds__(256) void gemm_nt(const float* __restrict__ A,
                                               const float* __restrict__ W,
                                               const float* __restrict__ bias,
                                               float* __restrict__ C,
                                               int M, int N, int K) {
    __shared__ __align__(16) float As[TK][TM + 4];
    __shared__ __align__(16) float Bs[TK][TN + 4];
    const int tid = threadIdx.x;
    const int m0 = blockIdx.x * TM;
    const int n0 = blockIdx.y * TN;
    const int tx = tid & 15;
    const int ty = tid >> 4;
    const int lr = tid >> 2;
    const int lk = (tid & 3) << 2;

    float acc[8][4];
    #pragma unroll
    for (int i = 0; i < 8; ++i)
        #pragma unroll
        for (int j = 0; j < 4; ++j) acc[i][j] = 0.f;

    for (int k0 = 0; k0 < K; k0 += TK) {
        const bool kok = (k0 + lk + 3) < K;
        #pragma unroll
        for (int h = 0; h < 2; ++h) {
            float4 v = make_float4(0.f, 0.f, 0.f, 0.f);
            int m = m0 + lr + 64 * h;
            if (kok) v = *reinterpret_cast<const float4*>(&A[(size_t)m * K + k0 + lk]);
            As[lk + 0][lr + 64 * h] = v.x;
            As[lk + 1][lr + 64 * h] = v.y;
            As[lk + 2][lr + 64 * h] = v.z;
            As[lk + 3][lr + 64 * h] = v.w;
        }
        {
            float4 v = make_float4(0.f, 0.f, 0.f, 0.f);
            int n = n0 + lr;
            if (kok && n < N) v = *reinterpret_cast<const float4*>(&W[(size_t)n * K + k0 + lk]);
            Bs[lk + 0][lr] = v.x;
            Bs[lk + 1][lr] = v.y;
            Bs[lk + 2][lr] = v.z;
            Bs[lk + 3][lr] = v.w;
        }
        __syncthreads();
        #pragma unroll
        for (int k = 0; k < TK; ++k) {
            float4 a0 = *reinterpret_cast<const float4*>(&As[k][ty * 8]);
            float4 a1 = *reinterpret_cast<const float4*>(&As[k][ty * 8 + 4]);
            float4 bv = *reinterpret_cast<const float4*>(&Bs[k][tx * 4]);
            float av[8] = {a0.x, a0.y, a0.z, a0.w, a1.x, a1.y, a1.z, a1.w};
            float bb[4] = {bv.x, bv.y, bv.z, bv.w};
            #pragma unroll
            for (int i = 0; i < 8; ++i)
                #pragma unroll
                for (int j = 0; j < 4; ++j) acc[i][j] += av[i] * bb[j];
        }
        __syncthreads();
    }
    #pragma unroll
    for (int i = 0; i < 8; ++i) {
        int m = m0 + ty * 8 + i;
        #pragma unroll
        for (int j = 0; j < 4; ++j) {
            int n = n0 + tx * 4 + j;
            if (n < N) C[(size_t)m * N + n] = acc[i][j] + (bias ? bias[n] : 0.f);
        }
    }
}

// ---------------- attention: scores -> alpha -> context_ -> beta logits ----------------
__global__ __launch_bounds__(256) void attn_kernel(const float* __restrict__ c_proj,
                                                   const float* __restrict__ a_proj,
                                                   const float* __restrict__ asp_emb,
                                                   const float* __restrict__ lin,
                                                   const float* __restrict__ Vatt,
                                                   const float* __restrict__ Vw,
                                                   const float* __restrict__ bVw,
                                                   float* __restrict__ blogit) {
    const int b = blockIdx.y;
    const int chunk = blockIdx.x;
    __shared__ float sA[16 * 300];
    __shared__ float sE[16 * 300];
    __shared__ float sV[300];
    __shared__ float sW[300];
    const int tid = threadIdx.x;
    for (int i = tid; i < 16 * 300; i += 256) {
        sA[i] = a_proj[b * 4800 + i];
        sE[i] = asp_emb[b * 4800 + i];
    }
    for (int i = tid; i < 300; i += 256) {
        sV[i] = Vatt[i];
        sW[i] = Vw[i];
    }
    __syncthreads();
    const int wave = tid >> 6, lane = tid & 63;
    const float bvw = bVw[0];
    for (int li = 0; li < 4; ++li) {
        const int l = chunk * 16 + wave * 4 + li;
        const float* crow = c_proj + (size_t)(b * L1_ + l) * 300;
        float cr[5];
        #pragma unroll
        for (int i = 0; i < 5; ++i) {
            int d = lane + 64 * i;
            cr[i] = (d < 300) ? crow[d] : 0.f;
        }
        float sc[16];
        #pragma unroll
        for (int m = 0; m < 16; ++m) {
            float s = 0.f;
            #pragma unroll
            for (int i = 0; i < 5; ++i) {
                int d = lane + 64 * i;
                if (d < 300) s += tanh_fast(cr[i] + sA[m * 300 + d]) * sV[d];
            }
            s = wred_sum(s);
            sc[m] = s;
        }
        float mx = sc[0];
        #pragma unroll
        for (int m = 1; m < 16; ++m) mx = fmaxf(mx, sc[m]);
        float den = 0.f;
        #pragma unroll
        for (int m = 0; m < 16; ++m) {
            sc[m] = __expf(sc[m] - mx);
            den += sc[m];
        }
        const float inv = 1.f / den;
        const float* lrow = lin + (size_t)(b * L1_ + l) * 300;
        float acc = 0.f;
        #pragma unroll
        for (int i = 0; i < 5; ++i) {
            int d = lane + 64 * i;
            if (d < 300) {
                float cd = 0.f;
                #pragma unroll
                for (int m = 0; m < 16; ++m) cd += sc[m] * sE[m * 300 + d];
                acc += tanh_fast(lrow[d] + cd * inv) * sW[d];
            }
        }
        acc = wred_sum(acc);
        if (lane == 0) blogit[b * L1_ + l] = acc + bvw;
    }
}

// ---------------- beta softmax over L1=512 per batch ----------------
__global__ __launch_bounds__(256) void beta_softmax_kernel(const float* __restrict__ x,
                                                           float* __restrict__ y) {
    const int b = blockIdx.x, tid = threadIdx.x;
    __shared__ float red[4];
    const int wave = tid >> 6, lane = tid & 63;
    float v0 = x[b * 512 + tid];
    float v1 = x[b * 512 + 256 + tid];
    float m = wred_max(fmaxf(v0, v1));
    if (lane == 0) red[wave] = m;
    __syncthreads();
    m = fmaxf(fmaxf(red[0], red[1]), fmaxf(red[2], red[3]));
    float e0 = __expf(v0 - m), e1 = __expf(v1 - m);
    float s = wred_sum(e0 + e1);
    __syncthreads();
    if (lane == 0) red[wave] = s;
    __syncthreads();
    s = red[0] + red[1] + red[2] + red[3];
    const float inv = 1.f / s;
    y[b * 512 + tid] = e0 * inv;
    y[b * 512 + 256 + tid] = e1 * inv;
}

// ---------------- GRU v10: gru7 protocol + reader waves 2-3 + lgkmcnt-only barriers ----------------
// Differences vs gru7 (1.90 ms, absmax 0.0):
//  (1) polls only on waves 2-3 (tid>=128, 1-2 packets each via dual-load):
//      polling lanes have NO outstanding publish store, so the poll's
//      s_waitcnt vmcnt(0) no longer serializes behind the store ACK.
//  (2) both barriers drain lgkmcnt only (LDS ordering), not vmcnt: publish
//      ACKs retire off the critical path.
//  (3) tight poll loop (no s_sleep — R8's backoff was the suspected cost).
// Math/protocol identical to the absmax-0.0 runs.
__global__ __launch_bounds__(256, 1) void gru10_kernel(const float* __restrict__ xg_f,
                                                       const float* __restrict__ xg_b,
                                                       const float* __restrict__ whh_f,
                                                       const float* __restrict__ whh_b,
                                                       const float* __restrict__ bhh_f,
                                                       const float* __restrict__ bhh_b,
                                                       const float* __restrict__ beta,
                                                       long long* __restrict__ slot, // [2][64][4][80]
                                                       float* __restrict__ senti) {
    const int s = blockIdx.x;    // slice 0..3 (owns h [75s, 75s+75))
    const int b = blockIdx.y;    // 0..31
    const int rev = blockIdx.z;  // 0..1
    const int g = rev * 32 + b;
    const float* xg  = rev ? xg_b : xg_f;
    const float* whh = rev ? whh_b : whh_f;
    const float* bhh = rev ? bhh_b : bhh_f;

    const int tid = threadIdx.x;
    const int e0 = s * 75;
    const bool act = tid < 225;
    const int gate = tid / 75;   // 0=r 1=z 2=n
    const int idx = tid % 75;

    __shared__ __align__(16) float hs[304];
    __shared__ float gg[3][80];

    // ---- weight row -> registers, asm-pinned (R5/R7-proven residency) ----
    float4 w4[75];
    float bh = 0.f;
    if (act) {
        const int row = gate * 300 + e0 + idx;
        bh = bhh[row];
        const float4* wp = reinterpret_cast<const float4*>(whh + (size_t)row * 300);
        #pragma unroll
        for (int j = 0; j < 75; ++j) w4[j] = wp[j];
    } else {
        #pragma unroll
        for (int j = 0; j < 75; ++j) w4[j] = make_float4(0.f, 0.f, 0.f, 0.f);
    }
    #pragma unroll
    for (int j = 0; j < 75; ++j)
        asm volatile("" : "+v"(w4[j].x), "+v"(w4[j].y), "+v"(w4[j].z), "+v"(w4[j].w));
    asm volatile("" : "+v"(bh));

    // reader setup (R8-proven mapping): tid>=128 polls foreign elements
    // i1 = tid-128 and (if valid) i2 = i1+128; element i -> slice fsl
    // (skipping own), offset fli
    int fsl1 = 0, fli1 = 0, fsl2 = 0, fli2 = 0;
    bool has2 = false;
    if (tid >= 128) {
        const int i1 = tid - 128;          // 0..127
        fsl1 = i1 / 75; if (fsl1 >= s) ++fsl1;
        fli1 = i1 % 75;
        const int i2 = i1 + 128;           // 128..255
        if (i2 < 225) {
            has2 = true;
            fsl2 = i2 / 75; if (fsl2 >= s) ++fsl2;
            fli2 = i2 % 75;
        } else {  // harmless duplicate of packet 1
            fsl2 = fsl1; fli2 = fli1;
        }
    }
    long long* wp0 = slot + ((size_t)g * 4 + s) * 80 + tid;             // writer base (tid<75)
    const long long* rb1 = slot + ((size_t)g * 4 + fsl1) * 80 + fli1;   // reader bases
    const long long* rb2 = slot + ((size_t)g * 4 + fsl2) * 80 + fli2;

    for (int i = tid; i < 304; i += 256) hs[i] = 0.f;
    float sacc = 0.f;
    int gaveup = 0;
    __syncthreads();

    const float4* hs4 = reinterpret_cast<const float4*>(hs);
    for (int step = 0; step < 512; ++step) {
        const int t = rev ? (511 - step) : step;
        // prefetch xg/beta (independent of h; latency hides under the matvec)
        float xr = 0.f, xz = 0.f, xn = 0.f, bt = 0.f;
        if (tid < 75) {
            const float* xrow = xg + (size_t)(b * 512 + t) * 900;
            const int e = e0 + tid;
            xr = xrow[e];
            xz = xrow[300 + e];
            xn = xrow[600 + e];
            bt = beta[b * 512 + t];
        }
        // matvec from pinned registers, 4 accumulators (identical order to R7)
        float a0 = 0.f, a1 = 0.f, a2 = 0.f, a3 = 0.f;
        #pragma unroll
        for (int j = 0; j < 72; j += 4) {
            float4 hv;
            hv = hs4[j];
            a0 = fmaf(w4[j].x, hv.x, a0); a0 = fmaf(w4[j].y, hv.y, a0);
            a0 = fmaf(w4[j].z, hv.z, a0); a0 = fmaf(w4[j].w, hv.w, a0);
            hv = hs4[j + 1];
            a1 = fmaf(w4[j + 1].x, hv.x, a1); a1 = fmaf(w4[j + 1].y, hv.y, a1);
            a1 = fmaf(w4[j + 1].z, hv.z, a1); a1 = fmaf(w4[j + 1].w, hv.w, a1);
            hv = hs4[j + 2];
            a2 = fmaf(w4[j + 2].x, hv.x, a2); a2 = fmaf(w4[j + 2].y, hv.y, a2);
            a2 = fmaf(w4[j + 2].z, hv.z, a2); a2 = fmaf(w4[j + 2].w, hv.w, a2);
            hv = hs4[j + 3];
            a3 = fmaf(w4[j + 3].x, hv.x, a3); a3 = fmaf(w4[j + 3].y, hv.y, a3);
            a3 = fmaf(w4[j + 3].z, hv.z, a3); a3 = fmaf(w4[j + 3].w, hv.w, a3);
        }
        {   // j = 72, 73, 74 tail
            float4 hv;
            hv = hs4[72];
            a0 = fmaf(w4[72].x, hv.x, a0); a0 = fmaf(w4[72].y, hv.y, a0);
            a0 = fmaf(w4[72].z, hv.z, a0); a0 = fmaf(w4[72].w, hv.w, a0);
            hv = hs4[73];
            a1 = fmaf(w4[73].x, hv.x, a1); a1 = fmaf(w4[73].y, hv.y, a1);
            a1 = fmaf(w4[73].z, hv.z, a1); a1 = fmaf(w4[73].w, hv.w, a1);
            hv = hs4[74];
            a2 = fmaf(w4[74].x, hv.x, a2); a2 = fmaf(w4[74].y, hv.y, a2);
            a2 = fmaf(w4[74].z, hv.z, a2); a2 = fmaf(w4[74].w, hv.w, a2);
        }
        const float acc = bh + ((a0 + a1) + (a2 + a3));
        if (act) gg[gate][idx] = acc;
        wg_barrier();
        if (step == 511) {
            // final step: only own-slice gates needed (no publish/poll)
            if (tid < 75) {
                const float rr = sigmoid_acc(xr + gg[0][tid]);
                const float zz = sigmoid_acc(xz + gg[1][tid]);
                const float nn = tanhf(xn + rr * gg[2][tid]);
                const float hn = (1.f - zz) * nn + zz * hs[e0 + tid];
                sacc = fmaf(bt, hn, sacc);
            }
            break;
        }
        // waves 0-1: gates + publish.  waves 2-3: poll (start immediately).
        if (tid < 75) {
            const int e = e0 + tid;
            const float rr = sigmoid_acc(xr + gg[0][tid]);
            const float zz = sigmoid_acc(xz + gg[1][tid]);
            const float nn = tanhf(xn + rr * gg[2][tid]);
            const float hn = (1.f - zz) * nn + zz * hs[e];
            sacc = fmaf(bt, hn, sacc);
            hs[e] = hn;
            long long pkt = ((long long)(unsigned)step << 32) |
                            (unsigned)__float_as_int(hn);
            store_pkt(wp0 + (size_t)(step & 1) * 64 * 4 * 80, pkt);
        } else if (tid >= 128) {
            const size_t po = (size_t)(step & 1) * 64 * 4 * 80;
            const long long* p1 = rb1 + po;
            const long long* p2 = rb2 + po;
            long long v1 = 0, v2 = 0;
            if (!gaveup) {
                load_pkt2(p1, p2, v1, v2);
                int it = 0;
                while (((int)(v1 >> 32)) != step || ((int)(v2 >> 32)) != step) {
                    if (++it >= (1 << 16)) { gaveup = 1; break; }
                    load_pkt2(p1, p2, v1, v2);
                }
            } else {
                load_pkt2(p1, p2, v1, v2);
            }
            hs[fsl1 * 75 + fli1] = __int_as_float((int)(v1 & 0xffffffffLL));
            if (has2) hs[fsl2 * 75 + fli2] = __int_as_float((int)(v2 & 0xffffffffLL));
        }
        wg_barrier();
    }
    if (tid < 75) senti[b * 600 + rev * 300 + e0 + tid] = sacc;
}

// ---------------- final logits: (32,600) x (3,600)^T + outb ----------------
__global__ __launch_bounds__(64) void logits_kernel(const float* __restrict__ senti,
                                                    const float* __restrict__ outW,
                                                    const float* __restrict__ outb,
                                                    float* __restrict__ out) {
    const int b = blockIdx.x, lane = threadIdx.x;
    for (int c = 0; c < 3; ++c) {
        float s = 0.f;
        for (int hh = lane; hh < 600; hh += 64) s += senti[b * 600 + hh] * outW[c * 600 + hh];
        s = wred_sum(s);
        if (lane == 0) out[b * 3 + c] = s + outb[c];
    }
}

extern "C" void kernel_launch(void* const* d_in, const int* in_sizes, int n_in,
                              void* d_out, int out_size, void* d_ws, size_t ws_size,
                              hipStream_t stream) {
    const int* ctx_ids = (const int*)d_in[0];
    const int* asp_ids = (const int*)d_in[1];
    // d_in[2], d_in[3]: masks (all ones, unused by reference)
    const float* emb   = (const float*)d_in[4];
    const float* Wc    = (const float*)d_in[5];
    const float* Wa    = (const float*)d_in[6];
    const float* Vatt  = (const float*)d_in[7];
    const float* Wlin  = (const float*)d_in[8];
    const float* blin  = (const float*)d_in[9];
    const float* Vw    = (const float*)d_in[10];
    const float* bVw   = (const float*)d_in[11];
    const float* wih_f = (const float*)d_in[12];
    const float* whh_f = (const float*)d_in[13];
    const float* bih_f = (const float*)d_in[14];
    const float* bhh_f = (const float*)d_in[15];
    const float* wih_b = (const float*)d_in[16];
    const float* whh_b = (const float*)d_in[17];
    const float* bih_b = (const float*)d_in[18];
    const float* bhh_b = (const float*)d_in[19];
    const float* outW  = (const float*)d_in[20];
    const float* outb  = (const float*)d_in[21];
    float* ws = (float*)d_ws;

    size_t o = 0;
    float* ctx_emb = ws + o; o += (size_t)B_ * L1_ * D_;
    float* asp_emb = ws + o; o += (size_t)B_ * L2_ * D_;
    float* c_proj  = ws + o; o += (size_t)B_ * L1_ * D_;
    float* a_proj  = ws + o; o += (size_t)B_ * L2_ * D_;
    float* lin_buf = ws + o; o += (size_t)B_ * L1_ * D_;
    float* xg_f    = ws + o; o += (size_t)B_ * L1_ * 3 * H_;
    float* xg_b    = ws + o; o += (size_t)B_ * L1_ * 3 * H_;
    float* blogit  = ws + o; o += (size_t)B_ * L1_;
    float* beta    = ws + o; o += (size_t)B_ * L1_;
    float* senti   = ws + o; o += (size_t)B_ * 2 * H_;
    o = (o + 1) & ~(size_t)1;                 // 8B-align the slot area
    long long* slot = (long long*)(ws + o);   // [2][64][4][80] packets
    const size_t slot_ll = (size_t)2 * 64 * 4 * 80;
    o += slot_ll * 2;

    hipMemsetAsync(slot, 0xFF, slot_ll * sizeof(long long), stream);

    dim3 blk(256);
    const int tot_ctx = B_ * L1_ * 75;
    const int tot_asp = B_ * L2_ * 75;
    gather_kernel<<<dim3((tot_ctx + 255) / 256), blk, 0, stream>>>(emb, ctx_ids, ctx_emb, tot_ctx);
    gather_kernel<<<dim3((tot_asp + 255) / 256), blk, 0, stream>>>(emb, asp_ids, asp_emb, tot_asp);

    gemm_nt<<<dim3(16384 / 128, 5), blk, 0, stream>>>(ctx_emb, Wc, nullptr, c_proj, 16384, 300, 300);
    gemm_nt<<<dim3(16384 / 128, 5), blk, 0, stream>>>(ctx_emb, Wlin, blin, lin_buf, 16384, 300, 300);
    gemm_nt<<<dim3(512 / 128, 5), blk, 0, stream>>>(asp_emb, Wa, nullptr, a_proj, 512, 300, 300);
    gemm_nt<<<dim3(16384 / 128, 15), blk, 0, stream>>>(ctx_emb, wih_f, bih_f, xg_f, 16384, 900, 300);
    gemm_nt<<<dim3(16384 / 128, 15), blk, 0, stream>>>(ctx_emb, wih_b, bih_b, xg_b, 16384, 900, 300);

    attn_kernel<<<dim3(32, 32), blk, 0, stream>>>(c_proj, a_proj, asp_emb, lin_buf, Vatt, Vw, bVw, blogit);
    beta_softmax_kernel<<<dim3(32), blk, 0, stream>>>(blogit, beta);
    gru10_kernel<<<dim3(4, 32, 2), blk, 0, stream>>>(xg_f, xg_b, whh_f, whh_b, bhh_f, bhh_b,
                                                     beta, slot, senti);
    logits_kernel<<<dim3(32), dim3(64), 0, stream>>>(senti, outW, outb, (float*)d_out);
}

// Round 14
// 2376.860 us; speedup vs baseline: 1.0393x; 1.0393x over previous
//
#include <hip/hip_runtime.h>

// Model: B=32, L1=512, L2=16, D=300, H=300, V=50000, C=3
// FINAL CONFIG (R7-exact): gru7 tag-carried LLC exchange (best of 4 measured
// variants: 1904 vs 1992/3877/1993 µs) + gemm_nt 128x64/8x4 high-occupancy
// GEMM (best of 3 measured variants). Session: 5900 -> 2372 µs.
#define B_  32
#define L1_ 512
#define L2_ 16
#define D_  300
#define H_  300

__device__ __forceinline__ float sigmoid_fast(float x) {
    return 1.0f / (1.0f + __expf(-x));
}
__device__ __forceinline__ float tanh_fast(float x) {
    x = fminf(fmaxf(x, -15.0f), 15.0f);
    float e = __expf(2.0f * x);
    return (e - 1.0f) / (e + 1.0f);
}
// accurate versions for the GRU recurrence (R4/R5/R7 evidence: large margin)
__device__ __forceinline__ float sigmoid_acc(float x) {
    return 1.0f / (1.0f + expf(-x));
}
__device__ __forceinline__ float wred_sum(float v) {
    #pragma unroll
    for (int off = 32; off > 0; off >>= 1) v += __shfl_xor(v, off);
    return v;
}
__device__ __forceinline__ float wred_max(float v) {
    #pragma unroll
    for (int off = 32; off > 0; off >>= 1) v = fmaxf(v, __shfl_xor(v, off));
    return v;
}

// device-coherent (LLC) 8-byte packet ops: sc0 sc1 = bypass L1+L2, no invalidates
__device__ __forceinline__ void store_pkt(long long* p, long long v) {
    asm volatile("global_store_dwordx2 %0, %1, off sc0 sc1" :: "v"(p), "v"(v) : "memory");
}
__device__ __forceinline__ long long load_pkt(const long long* p) {
    long long v;
    asm volatile("global_load_dwordx2 %0, %1, off sc0 sc1\n\t"
                 "s_waitcnt vmcnt(0)"
                 : "=v"(v) : "v"(p) : "memory");
    return v;
}

// ---------------- gather rows of emb (row length 300 = 75 float4) ----------------
__global__ __launch_bounds__(256) void gather_kernel(const float* __restrict__ emb,
                                                     const int* __restrict__ ids,
                                                     float* __restrict__ out, int total) {
    for (int i = blockIdx.x * 256 + threadIdx.x; i < total; i += gridDim.x * 256) {
        int row = i / 75, c = i % 75;
        int id = ids[row];
        reinterpret_cast<float4*>(out)[i] =
            reinterpret_cast<const float4*>(emb + (size_t)id * 300)[c];
    }
}

// ---------------- fp32 GEMM (R7-proven): C[M,N] = A[M,K] @ W[N,K]^T (+ bias) ----------------
// Measured-best config: 128x64 tile, 8x4 microtile, VGPR=40, 8 waves/SIMD.
// (R11/R12: 8x8-microtile 128x128 variants at ~3 waves/SIMD are net slower
// on these K=300 shapes despite higher FMA density.)
#define TM 128
#define TN 64
#define TK 16
__global__ __launch_bounds__(256) void gemm_nt(const float* __restrict__ A,
                                               const float* __restrict__ W,
                                               const float* __restrict__ bias,
                                               float* __restrict__ C,
                                               int M, int N, int K) {
    __shared__ __align__(16) float As[TK][TM + 4];
    __shared__ __align__(16) float Bs[TK][TN + 4];
    const int tid = threadIdx.x;
    const int m0 = blockIdx.x * TM;
    const int n0 = blockIdx.y * TN;
    const int tx = tid & 15;
    const int ty = tid >> 4;
    const int lr = tid >> 2;
    const int lk = (tid & 3) << 2;

    float acc[8][4];
    #pragma unroll
    for (int i = 0; i < 8; ++i)
        #pragma unroll
        for (int j = 0; j < 4; ++j) acc[i][j] = 0.f;

    for (int k0 = 0; k0 < K; k0 += TK) {
        const bool kok = (k0 + lk + 3) < K;
        #pragma unroll
        for (int h = 0; h < 2; ++h) {
            float4 v = make_float4(0.f, 0.f, 0.f, 0.f);
            int m = m0 + lr + 64 * h;
            if (kok) v = *reinterpret_cast<const float4*>(&A[(size_t)m * K + k0 + lk]);
            As[lk + 0][lr + 64 * h] = v.x;
            As[lk + 1][lr + 64 * h] = v.y;
            As[lk + 2][lr + 64 * h] = v.z;
            As[lk + 3][lr + 64 * h] = v.w;
        }
        {
            float4 v = make_float4(0.f, 0.f, 0.f, 0.f);
            int n = n0 + lr;
            if (kok && n < N) v = *reinterpret_cast<const float4*>(&W[(size_t)n * K + k0 + lk]);
            Bs[lk + 0][lr] = v.x;
            Bs[lk + 1][lr] = v.y;
            Bs[lk + 2][lr] = v.z;
            Bs[lk + 3][lr] = v.w;
        }
        __syncthreads();
        #pragma unroll
        for (int k = 0; k < TK; ++k) {
            float4 a0 = *reinterpret_cast<const float4*>(&As[k][ty * 8]);
            float4 a1 = *reinterpret_cast<const float4*>(&As[k][ty * 8 + 4]);
            float4 bv = *reinterpret_cast<const float4*>(&Bs[k][tx * 4]);
            float av[8] = {a0.x, a0.y, a0.z, a0.w, a1.x, a1.y, a1.z, a1.w};
            float bb[4] = {bv.x, bv.y, bv.z, bv.w};
            #pragma unroll
            for (int i = 0; i < 8; ++i)
                #pragma unroll
                for (int j = 0; j < 4; ++j) acc[i][j] += av[i] * bb[j];
        }
        __syncthreads();
    }
    #pragma unroll
    for (int i = 0; i < 8; ++i) {
        int m = m0 + ty * 8 + i;
        #pragma unroll
        for (int j = 0; j < 4; ++j) {
            int n = n0 + tx * 4 + j;
            if (n < N) C[(size_t)m * N + n] = acc[i][j] + (bias ? bias[n] : 0.f);
        }
    }
}

// ---------------- attention: scores -> alpha -> context_ -> beta logits ----------------
__global__ __launch_bounds__(256) void attn_kernel(const float* __restrict__ c_proj,
                                                   const float* __restrict__ a_proj,
                                                   const float* __restrict__ asp_emb,
                                                   const float* __restrict__ lin,
                                                   const float* __restrict__ Vatt,
                                                   const float* __restrict__ Vw,
                                                   const float* __restrict__ bVw,
                                                   float* __restrict__ blogit) {
    const int b = blockIdx.y;
    const int chunk = blockIdx.x;
    __shared__ float sA[16 * 300];
    __shared__ float sE[16 * 300];
    __shared__ float sV[300];
    __shared__ float sW[300];
    const int tid = threadIdx.x;
    for (int i = tid; i < 16 * 300; i += 256) {
        sA[i] = a_proj[b * 4800 + i];
        sE[i] = asp_emb[b * 4800 + i];
    }
    for (int i = tid; i < 300; i += 256) {
        sV[i] = Vatt[i];
        sW[i] = Vw[i];
    }
    __syncthreads();
    const int wave = tid >> 6, lane = tid & 63;
    const float bvw = bVw[0];
    for (int li = 0; li < 4; ++li) {
        const int l = chunk * 16 + wave * 4 + li;
        const float* crow = c_proj + (size_t)(b * L1_ + l) * 300;
        float cr[5];
        #pragma unroll
        for (int i = 0; i < 5; ++i) {
            int d = lane + 64 * i;
            cr[i] = (d < 300) ? crow[d] : 0.f;
        }
        float sc[16];
        #pragma unroll
        for (int m = 0; m < 16; ++m) {
            float s = 0.f;
            #pragma unroll
            for (int i = 0; i < 5; ++i) {
                int d = lane + 64 * i;
                if (d < 300) s += tanh_fast(cr[i] + sA[m * 300 + d]) * sV[d];
            }
            s = wred_sum(s);
            sc[m] = s;
        }
        float mx = sc[0];
        #pragma unroll
        for (int m = 1; m < 16; ++m) mx = fmaxf(mx, sc[m]);
        float den = 0.f;
        #pragma unroll
        for (int m = 0; m < 16; ++m) {
            sc[m] = __expf(sc[m] - mx);
            den += sc[m];
        }
        const float inv = 1.f / den;
        const float* lrow = lin + (size_t)(b * L1_ + l) * 300;
        float acc = 0.f;
        #pragma unroll
        for (int i = 0; i < 5; ++i) {
            int d = lane + 64 * i;
            if (d < 300) {
                float cd = 0.f;
                #pragma unroll
                for (int m = 0; m < 16; ++m) cd += sc[m] * sE[m * 300 + d];
                acc += tanh_fast(lrow[d] + cd * inv) * sW[d];
            }
        }
        acc = wred_sum(acc);
        if (lane == 0) blogit[b * L1_ + l] = acc + bvw;
    }
}

// ---------------- beta softmax over L1=512 per batch ----------------
__global__ __launch_bounds__(256) void beta_softmax_kernel(const float* __restrict__ x,
                                                           float* __restrict__ y) {
    const int b = blockIdx.x, tid = threadIdx.x;
    __shared__ float red[4];
    const int wave = tid >> 6, lane = tid & 63;
    float v0 = x[b * 512 + tid];
    float v1 = x[b * 512 + 256 + tid];
    float m = wred_max(fmaxf(v0, v1));
    if (lane == 0) red[wave] = m;
    __syncthreads();
    m = fmaxf(fmaxf(red[0], red[1]), fmaxf(red[2], red[3]));
    float e0 = __expf(v0 - m), e1 = __expf(v1 - m);
    float s = wred_sum(e0 + e1);
    __syncthreads();
    if (lane == 0) red[wave] = s;
    __syncthreads();
    s = red[0] + red[1] + red[2] + red[3];
    const float inv = 1.f / s;
    y[b * 512 + tid] = e0 * inv;
    y[b * 512 + 256 + tid] = e1 * inv;
}

// ---------------- GRU v7 (measured best: 1904 µs, absmax 0.0) ----------------
// grid (4,32,2), 256 threads, 1 block/CU. NO barrier, NO atomics: each h
// element is published as an 8B packet {f32 value, i32 step} with a
// device-coherent sc0 sc1 store; readers issue tagged loads and retry until
// tag==step. Tag rides in the same aligned 8B transaction -> no fence,
// placement-independent. Slots double-buffered by step parity; memset 0xFF
// per launch. Structural floor: 512 serial LLC exchange rounds at ~3.7 µs
// (publish-visible 375ns + drift-driven ~3.5 poll RTs + ~1µs compute);
// variants R8/R9/R13 all measured slower.
__global__ __launch_bounds__(256, 1) void gru7_kernel(const float* __restrict__ xg_f,
                                                      const float* __restrict__ xg_b,
                                                      const float* __restrict__ whh_f,
                                                      const float* __restrict__ whh_b,
                                                      const float* __restrict__ bhh_f,
                                                      const float* __restrict__ bhh_b,
                                                      const float* __restrict__ beta,
                                                      long long* __restrict__ slot, // [2][64][4][80]
                                                      float* __restrict__ senti) {
    const int s = blockIdx.x;    // slice 0..3 (owns h [75s, 75s+75))
    const int b = blockIdx.y;    // 0..31
    const int rev = blockIdx.z;  // 0..1
    const int g = rev * 32 + b;
    const float* xg  = rev ? xg_b : xg_f;
    const float* whh = rev ? whh_b : whh_f;
    const float* bhh = rev ? bhh_b : bhh_f;

    const int tid = threadIdx.x;
    const int e0 = s * 75;
    const bool act = tid < 225;
    const int gate = tid / 75;   // 0=r 1=z 2=n
    const int idx = tid % 75;

    __shared__ __align__(16) float hs[304];
    __shared__ float gg[3][80];

    // ---- weight row -> registers, asm-pinned ----
    float4 w4[75];
    float bh = 0.f;
    if (act) {
        const int row = gate * 300 + e0 + idx;
        bh = bhh[row];
        const float4* wp = reinterpret_cast<const float4*>(whh + (size_t)row * 300);
        #pragma unroll
        for (int j = 0; j < 75; ++j) w4[j] = wp[j];
    } else {
        #pragma unroll
        for (int j = 0; j < 75; ++j) w4[j] = make_float4(0.f, 0.f, 0.f, 0.f);
    }
    #pragma unroll
    for (int j = 0; j < 75; ++j)
        asm volatile("" : "+v"(w4[j].x), "+v"(w4[j].y), "+v"(w4[j].z), "+v"(w4[j].w));
    asm volatile("" : "+v"(bh));

    // reader setup: tid<225 owns one foreign element
    int fsl = 0, fli = 0;
    if (tid < 225) {
        fsl = tid / 75;
        if (fsl >= s) ++fsl;           // skip own slice
        fli = tid % 75;
    }
    long long* wp0 = slot + ((size_t)g * 4 + s) * 80 + tid;            // writer base
    const long long* rbase = slot + ((size_t)g * 4 + fsl) * 80 + fli;  // reader base

    for (int i = tid; i < 304; i += 256) hs[i] = 0.f;
    float sacc = 0.f;
    int gaveup = 0;
    __syncthreads();

    const float4* hs4 = reinterpret_cast<const float4*>(hs);
    for (int step = 0; step < 512; ++step) {
        const int t = rev ? (511 - step) : step;
        // prefetch xg/beta (independent of h; latency hides under the matvec)
        float xr = 0.f, xz = 0.f, xn = 0.f, bt = 0.f;
        if (tid < 75) {
            const float* xrow = xg + (size_t)(b * 512 + t) * 900;
            const int e = e0 + tid;
            xr = xrow[e];
            xz = xrow[300 + e];
            xn = xrow[600 + e];
            bt = beta[b * 512 + t];
        }
        // matvec from pinned registers, 4 accumulators
        float a0 = 0.f, a1 = 0.f, a2 = 0.f, a3 = 0.f;
        #pragma unroll
        for (int j = 0; j < 72; j += 4) {
            float4 hv;
            hv = hs4[j];
            a0 = fmaf(w4[j].x, hv.x, a0); a0 = fmaf(w4[j].y, hv.y, a0);
            a0 = fmaf(w4[j].z, hv.z, a0); a0 = fmaf(w4[j].w, hv.w, a0);
            hv = hs4[j + 1];
            a1 = fmaf(w4[j + 1].x, hv.x, a1); a1 = fmaf(w4[j + 1].y, hv.y, a1);
            a1 = fmaf(w4[j + 1].z, hv.z, a1); a1 = fmaf(w4[j + 1].w, hv.w, a1);
            hv = hs4[j + 2];
            a2 = fmaf(w4[j + 2].x, hv.x, a2); a2 = fmaf(w4[j + 2].y, hv.y, a2);
            a2 = fmaf(w4[j + 2].z, hv.z, a2); a2 = fmaf(w4[j + 2].w, hv.w, a2);
            hv = hs4[j + 3];
            a3 = fmaf(w4[j + 3].x, hv.x, a3); a3 = fmaf(w4[j + 3].y, hv.y, a3);
            a3 = fmaf(w4[j + 3].z, hv.z, a3); a3 = fmaf(w4[j + 3].w, hv.w, a3);
        }
        {   // j = 72, 73, 74 tail
            float4 hv;
            hv = hs4[72];
            a0 = fmaf(w4[72].x, hv.x, a0); a0 = fmaf(w4[72].y, hv.y, a0);
            a0 = fmaf(w4[72].z, hv.z, a0); a0 = fmaf(w4[72].w, hv.w, a0);
            hv = hs4[73];
            a1 = fmaf(w4[73].x, hv.x, a1); a1 = fmaf(w4[73].y, hv.y, a1);
            a1 = fmaf(w4[73].z, hv.z, a1); a1 = fmaf(w4[73].w, hv.w, a1);
            hv = hs4[74];
            a2 = fmaf(w4[74].x, hv.x, a2); a2 = fmaf(w4[74].y, hv.y, a2);
            a2 = fmaf(w4[74].z, hv.z, a2); a2 = fmaf(w4[74].w, hv.w, a2);
        }
        const float acc = bh + ((a0 + a1) + (a2 + a3));
        if (act) gg[gate][idx] = acc;
        __syncthreads();
        // own-slice gate update; publish packet {h, step}
        if (tid < 75) {
            const int e = e0 + tid;
            const float rr = sigmoid_acc(xr + gg[0][tid]);
            const float zz = sigmoid_acc(xz + gg[1][tid]);
            const float nn = tanhf(xn + rr * gg[2][tid]);
            const float hn = (1.f - zz) * nn + zz * hs[e];
            sacc = fmaf(bt, hn, sacc);
            hs[e] = hn;
            if (step < 511) {
                long long pkt = ((long long)(unsigned)step << 32) |
                                (unsigned)__float_as_int(hn);
                store_pkt(wp0 + (size_t)(step & 1) * 64 * 4 * 80, pkt);
            }
        }
        if (step == 511) break;
        // tagged gather of the 3 foreign slices
        if (tid < 225) {
            const long long* p = rbase + (size_t)(step & 1) * 64 * 4 * 80;
            long long v = 0;
            if (!gaveup) {
                int ok = 0;
                for (int it = 0; it < (1 << 16); ++it) {
                    v = load_pkt(p);
                    if (((int)(v >> 32)) == step) { ok = 1; break; }
                }
                if (!ok) gaveup = 1;   // sticky: never hang; keep last value
            } else {
                v = load_pkt(p);
            }
            hs[fsl * 75 + fli] = __int_as_float((int)(v & 0xffffffffLL));
        }
        __syncthreads();
    }
    if (tid < 75) senti[b * 600 + rev * 300 + e0 + tid] = sacc;
}

// ---------------- final logits: (32,600) x (3,600)^T + outb ----------------
__global__ __launch_bounds__(64) void logits_kernel(const float* __restrict__ senti,
                                                    const float* __restrict__ outW,
                                                    const float* __restrict__ outb,
                                                    float* __restrict__ out) {
    const int b = blockIdx.x, lane = threadIdx.x;
    for (int c = 0; c < 3; ++c) {
        float s = 0.f;
        for (int hh = lane; hh < 600; hh += 64) s += senti[b * 600 + hh] * outW[c * 600 + hh];
        s = wred_sum(s);
        if (lane == 0) out[b * 3 + c] = s + outb[c];
    }
}

extern "C" void kernel_launch(void* const* d_in, const int* in_sizes, int n_in,
                              void* d_out, int out_size, void* d_ws, size_t ws_size,
                              hipStream_t stream) {
    const int* ctx_ids = (const int*)d_in[0];
    const int* asp_ids = (const int*)d_in[1];
    // d_in[2], d_in[3]: masks (all ones, unused by reference)
    const float* emb   = (const float*)d_in[4];
    const float* Wc    = (const float*)d_in[5];
    const float* Wa    = (const float*)d_in[6];
    const float* Vatt  = (const float*)d_in[7];
    const float* Wlin  = (const float*)d_in[8];
    const float* blin  = (const float*)d_in[9];
    const float* Vw    = (const float*)d_in[10];
    const float* bVw   = (const float*)d_in[11];
    const float* wih_f = (const float*)d_in[12];
    const float* whh_f = (const float*)d_in[13];
    const float* bih_f = (const float*)d_in[14];
    const float* bhh_f = (const float*)d_in[15];
    const float* wih_b = (const float*)d_in[16];
    const float* whh_b = (const float*)d_in[17];
    const float* bih_b = (const float*)d_in[18];
    const float* bhh_b = (const float*)d_in[19];
    const float* outW  = (const float*)d_in[20];
    const float* outb  = (const float*)d_in[21];
    float* ws = (float*)d_ws;

    size_t o = 0;
    float* ctx_emb = ws + o; o += (size_t)B_ * L1_ * D_;
    float* asp_emb = ws + o; o += (size_t)B_ * L2_ * D_;
    float* c_proj  = ws + o; o += (size_t)B_ * L1_ * D_;
    float* a_proj  = ws + o; o += (size_t)B_ * L2_ * D_;
    float* lin_buf = ws + o; o += (size_t)B_ * L1_ * D_;
    float* xg_f    = ws + o; o += (size_t)B_ * L1_ * 3 * H_;
    float* xg_b    = ws + o; o += (size_t)B_ * L1_ * 3 * H_;
    float* blogit  = ws + o; o += (size_t)B_ * L1_;
    float* beta    = ws + o; o += (size_t)B_ * L1_;
    float* senti   = ws + o; o += (size_t)B_ * 2 * H_;
    o = (o + 1) & ~(size_t)1;                 // 8B-align the slot area
    long long* slot = (long long*)(ws + o);   // [2][64][4][80] packets
    const size_t slot_ll = (size_t)2 * 64 * 4 * 80;
    o += slot_ll * 2;

    hipMemsetAsync(slot, 0xFF, slot_ll * sizeof(long long), stream);

    dim3 blk(256);
    const int tot_ctx = B_ * L1_ * 75;
    const int tot_asp = B_ * L2_ * 75;
    gather_kernel<<<dim3((tot_ctx + 255) / 256), blk, 0, stream>>>(emb, ctx_ids, ctx_emb, tot_ctx);
    gather_kernel<<<dim3((tot_asp + 255) / 256), blk, 0, stream>>>(emb, asp_ids, asp_emb, tot_asp);

    gemm_nt<<<dim3(16384 / 128, 5), blk, 0, stream>>>(ctx_emb, Wc, nullptr, c_proj, 16384, 300, 300);
    gemm_nt<<<dim3(16384 / 128, 5), blk, 0, stream>>>(ctx_emb, Wlin, blin, lin_buf, 16384, 300, 300);
    gemm_nt<<<dim3(512 / 128, 5), blk, 0, stream>>>(asp_emb, Wa, nullptr, a_proj, 512, 300, 300);
    gemm_nt<<<dim3(16384 / 128, 15), blk, 0, stream>>>(ctx_emb, wih_f, bih_f, xg_f, 16384, 900, 300);
    gemm_nt<<<dim3(16384 / 128, 15), blk, 0, stream>>>(ctx_emb, wih_b, bih_b, xg_b, 16384, 900, 300);

    attn_kernel<<<dim3(32, 32), blk, 0, stream>>>(c_proj, a_proj, asp_emb, lin_buf, Vatt, Vw, bVw, blogit);
    beta_softmax_kernel<<<dim3(32), blk, 0, stream>>>(blogit, beta);
    gru7_kernel<<<dim3(4, 32, 2), blk, 0, stream>>>(xg_f, xg_b, whh_f, whh_b, bhh_f, bhh_b,
                                                    beta, slot, senti);
    logits_kernel<<<dim3(32), dim3(64), 0, stream>>>(senti, outW, outb, (float*)d_out);
}